// Round 15
// baseline (704.032 us; speedup 1.0000x reference)
//
#include <hip/hip_runtime.h>
#include <hip/hip_bf16.h>
#include <stdint.h>

#define U_N   100000
#define I_N   200000
#define NN    300000
#define DD    64
#define NNZ_N 6400000
#define BB    4096
#define CHUNK 4096
#define NB    ((NN + CHUNK - 1) / CHUNK)   // 74 scan blocks
#define NBK   74                           // coarse buckets of 4096 rows
#define EPB   8192                         // edges per pass-1 block (512 thr x 16)
#define NSB   1184                         // 74*16 sub-buckets of 256 rows
#define SUBCAP 6656                        // max edges per sub-bucket (mean 5406, +17 sigma)
#define BKCAP  94208                       // fixed bucket capacity = 23*4096 (mean 87381, +23 sigma)
#define BKBLK  23                          // p2r blocks per bucket = BKCAP/4096
#define LBLK   48000                       // spmm_list grid: 192000 slots >= nlist
#define P1B   ((NNZ_N + EPB - 1) / EPB)    // 782 p1 blocks
#define PACKB ((NN * 16) / 512)            // 9375 pack blocks (512 thr)
#define ACCB  ((2 * BB * 32) / 512)        // 512 init_acc blocks (512 thr)
#define CPB   ((NN + 1023) / 1024)         // 293 compact blocks (1024 thr, in fused2)

typedef unsigned short u16;
typedef unsigned int   u32;
typedef float vf2 __attribute__((ext_vector_type(2)));

__device__ __forceinline__ u16 f2bf(float f) {
    u32 u = __float_as_uint(f);
    u32 r = (u + 0x7FFFu + ((u >> 16) & 1u)) >> 16;
    return (u16)r;
}

// ---------------- fp8 e4m3fn encode/decode (OCP; HW converts on gfx950) ----------------

#if __has_builtin(__builtin_amdgcn_cvt_pk_f32_fp8) && __has_builtin(__builtin_amdgcn_cvt_pk_fp8_f32)
#define FP8_HW 1
#else
#define FP8_HW 0
#endif

__device__ __forceinline__ u32 enc1_fp8(float f) {
    float af = fabsf(f);
    u32 s = (__float_as_uint(f) >> 31) << 7;
    if (af >= 0.015625f) {
        u32 au = __float_as_uint(af);
        u32 r = au + 0x7FFFFu + ((au >> 20) & 1u);
        u32 e = (r >> 23) - 120u;
        u32 m = (r >> 20) & 7u;
        if (e > 15u) { e = 15u; m = 6u; }
        return s | (e << 3) | m;
    } else {
        u32 q = (u32)__float2int_rn(af * 512.0f);   // RNE into subnormal grid 2^-9
        return s | q;
    }
}

__device__ __forceinline__ u32 pack4_fp8(float a, float b, float c, float d) {
#if FP8_HW
    u32 w = 0;
    w = (u32)__builtin_amdgcn_cvt_pk_fp8_f32(a, b, (int)w, false);
    w = (u32)__builtin_amdgcn_cvt_pk_fp8_f32(c, d, (int)w, true);
    return w;
#else
    return enc1_fp8(a) | (enc1_fp8(b) << 8) | (enc1_fp8(c) << 16) | (enc1_fp8(d) << 24);
#endif
}

__device__ __forceinline__ float dec1_fp8(u32 b) {
    u32 s = (b & 0x80u) << 24;
    u32 e = (b >> 3) & 15u;
    u32 m = b & 7u;
    float mag = e ? __uint_as_float(((e + 120u) << 23) | (m << 20))
                  : (float)m * 0.001953125f;   // 2^-9
    return __uint_as_float(__float_as_uint(mag) | s);
}

__device__ __forceinline__ void dec_fp8x4(u32 w, float* f) {
#if FP8_HW
    vf2 lo = __builtin_amdgcn_cvt_pk_f32_fp8((int)w, false);
    vf2 hi = __builtin_amdgcn_cvt_pk_f32_fp8((int)w, true);
    f[0] = lo[0]; f[1] = lo[1]; f[2] = hi[0]; f[3] = hi[1];
#else
    f[0] = dec1_fp8(w & 255u); f[1] = dec1_fp8((w >> 8) & 255u);
    f[2] = dec1_fp8((w >> 16) & 255u); f[3] = dec1_fp8(w >> 24);
#endif
}

// ---------------- setup: zero mark/bmark/nlist + bucket cursor init --------

__global__ void setup_k(unsigned char* __restrict__ mark, unsigned char* __restrict__ bmark,
                        int* __restrict__ nlist, int* __restrict__ bkt_cursor) {
    int tid = blockIdx.x * 256 + threadIdx.x;
    if (tid < NN / 4) { ((u32*)mark)[tid] = 0; ((u32*)bmark)[tid] = 0; }
    if (tid < NBK) bkt_cursor[tid] = tid * BKCAP;
    if (tid == NN / 4) nlist[0] = 0;
}

// bmark: batch-node flags (read by p1's frontier-marking and spmm1's bf16 gate)

__global__ void bmark_k(const int* __restrict__ user_idx, const int* __restrict__ item_idx,
                        unsigned char* __restrict__ mark, unsigned char* __restrict__ bmark) {
    int slot = blockIdx.x * 256 + threadIdx.x;
    if (slot >= 2 * BB) return;
    int r = (slot < BB) ? user_idx[slot] : U_N + item_idx[slot - BB];
    bmark[r] = 1;
    mark[r] = 1;
}

// ---------------- fused1: p1 bucket scatter + frontier mark + pack1 fp8 + init_acc ----
// 512-thread blocks: p1's per-bucket scatter chunk ~880B contiguous (R8/R10
// mechanism). Per-thread depth stays 16 (R3/R5: deeper starves VGPRs).
// payload: bed[p] = { pk = (row&4095)<<19 | col, val } -- ONE 8B store per edge.

__global__ __launch_bounds__(512) void fused1_k(const int* __restrict__ adj_row,
                                                const int* __restrict__ adj_col,
                                                const float* __restrict__ adj_val,
                                                int* __restrict__ bkt_cursor,
                                                int2* __restrict__ bed,
                                                const unsigned char* __restrict__ bmark,
                                                unsigned char* __restrict__ mark,
                                                const float* __restrict__ ue_on,
                                                const float* __restrict__ ie_on,
                                                const float* __restrict__ ue_tg,
                                                const float* __restrict__ ie_tg,
                                                unsigned char* __restrict__ x0f,
                                                const int* __restrict__ user_idx,
                                                const int* __restrict__ item_idx,
                                                float* __restrict__ out_acc) {
    __shared__ int lcnt[NBK];
    __shared__ int lbase[NBK];
    int bid = blockIdx.x;
    if (bid < P1B) {
        // ---- p1 body (512 threads x 16 edges) ----
        int base = bid * EPB;
        for (int i = threadIdx.x; i < NBK; i += 512) lcnt[i] = 0;
        __syncthreads();
        u32 pk[16]; float vv[16]; int bb[16]; int rk[16];
#pragma unroll
        for (int j = 0; j < 16; j++) {
            int e = base + j * 512 + threadIdx.x;
            bb[j] = -1;
            if (e < NNZ_N) {
                int r = adj_row[e];
                int c = adj_col[e];
                vv[j] = adj_val[e];
                int b = r >> 12;
                pk[j] = ((u32)(r & 4095) << 19) | (u32)c;
                bb[j] = b;
                rk[j] = atomicAdd(&lcnt[b], 1);
                if (bmark[r]) mark[c] = 1;   // fused frontier mark
            }
        }
        __syncthreads();
        for (int i = threadIdx.x; i < NBK; i += 512)
            lbase[i] = atomicAdd(&bkt_cursor[i], lcnt[i]);
        __syncthreads();
#pragma unroll
        for (int j = 0; j < 16; j++) {
            if (bb[j] >= 0) {
                int p = lbase[bb[j]] + rk[j];
                bed[p] = make_int2((int)pk[j], __float_as_int(vv[j]));
            }
        }
        return;
    }
    bid -= P1B;
    if (bid < PACKB) {
        // ---- pack1 body: x0 as fp8 e4m3fn [N,128] ----
        int tid = bid * 512 + threadIdx.x;   // NN*16 threads
        int n = tid >> 4;
        int t = tid & 15;
        if (n >= NN) return;
        const float* src;
        int soff;
        if (t < 8) {
            soff = t * 8;
            src = (n < U_N) ? ue_on + (size_t)n * 64 : ie_on + (size_t)(n - U_N) * 64;
        } else {
            soff = (t - 8) * 8;
            src = (n < U_N) ? ue_tg + (size_t)n * 64 : ie_tg + (size_t)(n - U_N) * 64;
        }
        float4 f0 = *(const float4*)(src + soff);
        float4 f1 = *(const float4*)(src + soff + 4);
        uint2 o;
        o.x = pack4_fp8(f0.x, f0.y, f0.z, f0.w);
        o.y = pack4_fp8(f1.x, f1.y, f1.z, f1.w);
        *(uint2*)(x0f + (size_t)n * 128 + t * 8) = o;
        return;
    }
    bid -= PACKB;
    {
        // ---- init_acc body ----
        int t = bid * 512 + threadIdx.x;   // 2B*32 threads
        int slot = t >> 5;
        int j = t & 31;
        if (slot >= 2 * BB) return;
        int node = (slot < BB) ? user_idx[slot] : U_N + item_idx[slot - BB];
        const float* src;
        int soff, doff;
        if (j < 16) {
            soff = j * 4; doff = j * 4;
            src = (node < U_N) ? ue_on + (size_t)node * 64 : ie_on + (size_t)(node - U_N) * 64;
        } else {
            soff = (j - 16) * 4; doff = 64 + (j - 16) * 4;
            src = (node < U_N) ? ue_tg + (size_t)node * 64 : ie_tg + (size_t)(node - U_N) * 64;
        }
        float4 f = *(const float4*)(src + soff);
        *(float4*)(out_acc + (size_t)slot * 128 + doff) = f;
    }
}

// ---------------- fused2: per-bucket LDS histogram + bucket scan + frontier compact ----
// blocks [0,NBK): histogram (int4 pair-loads x4 unroll, 8 edges in flight/thread);
// block NBK: bucket-total exclusive scan; blocks NBK+1..NBK+CPB: compact (1024-thr).

__global__ __launch_bounds__(1024) void fused2_k(const int* __restrict__ bkt_cursor,
                                                 const int2* __restrict__ bed,
                                                 int* __restrict__ cnt,
                                                 int* __restrict__ bsums,
                                                 int* __restrict__ row_ptr,
                                                 const unsigned char* __restrict__ mark,
                                                 int* __restrict__ list2,
                                                 int* __restrict__ nlist) {
    if (blockIdx.x < NBK) {
        __shared__ int h[4096];
        int b = blockIdx.x;
        int base = b * BKCAP;
        int e1 = bkt_cursor[b];            // base + cnt_b after p1
        int len = e1 - base;
        for (int j = threadIdx.x; j < 4096; j += 1024) h[j] = 0;
        __syncthreads();
        const int4* bed4 = (const int4*)(bed + base);   // edge pairs (BKCAP even -> aligned)
        int np = len >> 1;
        int t = threadIdx.x;
        int i = t;
        for (; i + 3072 < np; i += 4096) {
            int4 a  = bed4[i];
            int4 b2 = bed4[i + 1024];
            int4 c2 = bed4[i + 2048];
            int4 d2 = bed4[i + 3072];
            atomicAdd(&h[(u32)a.x  >> 19], 1); atomicAdd(&h[(u32)a.z  >> 19], 1);
            atomicAdd(&h[(u32)b2.x >> 19], 1); atomicAdd(&h[(u32)b2.z >> 19], 1);
            atomicAdd(&h[(u32)c2.x >> 19], 1); atomicAdd(&h[(u32)c2.z >> 19], 1);
            atomicAdd(&h[(u32)d2.x >> 19], 1); atomicAdd(&h[(u32)d2.z >> 19], 1);
        }
        for (; i < np; i += 1024) {
            int4 a = bed4[i];
            atomicAdd(&h[(u32)a.x >> 19], 1); atomicAdd(&h[(u32)a.z >> 19], 1);
        }
        if (t == 0 && (len & 1)) atomicAdd(&h[(u32)bed[e1 - 1].x >> 19], 1);
        __syncthreads();
        int rb = b << 12;
        for (int j = threadIdx.x; j < 4096; j += 1024) {
            int idx = rb + j;
            if (idx < NN) cnt[idx] = h[j];
        }
    } else if (blockIdx.x == NBK) {
        __shared__ int sh[128];
        int t = threadIdx.x;
        int v = 0;
        if (t < 128) {
            v = (t < NB) ? bkt_cursor[t] - t * BKCAP : 0;
            sh[t] = v;
        }
        __syncthreads();
        for (int o = 1; o < 128; o <<= 1) {
            int tmp = 0;
            if (t < 128 && t >= o) tmp = sh[t - o];
            __syncthreads();
            if (t < 128) sh[t] += tmp;
            __syncthreads();
        }
        if (t < NB) bsums[t] = sh[t] - v;   // exclusive
        if (t == 127) row_ptr[NN] = sh[127]; // total = NNZ
    } else {
        // ---- compact body (frontier list from mark) ----
        int i = (blockIdx.x - NBK - 1) * 1024 + threadIdx.x;
        int lane = threadIdx.x & 63;
        int m = (i < NN) ? (int)mark[i] : 0;
        unsigned long long b = __ballot(m != 0);
        int pre = __popcll(b & ((1ull << lane) - 1ull));
        int tot = __popcll(b);
        int base = 0;
        if (lane == 0 && tot) base = atomicAdd(nlist, tot);
        base = __shfl(base, 0);
        if (m) list2[base + pre] = i;
    }
}

// scan3 also seeds sub_cursor (fused former subinit_k).
__global__ void scan3_k(const int* __restrict__ cnt, const int* __restrict__ bsums,
                        int* __restrict__ row_ptr, int* __restrict__ sub_cursor) {
    __shared__ int tsum[256];
    int base = blockIdx.x * CHUNK;
    int loc[16];
    int s = 0;
#pragma unroll
    for (int j = 0; j < 16; j++) {
        int idx = base + threadIdx.x * 16 + j;
        int c = (idx < NN) ? cnt[idx] : 0;
        loc[j] = s;
        s += c;
    }
    tsum[threadIdx.x] = s;
    __syncthreads();
    int v = s;
    for (int o = 1; o < 256; o <<= 1) {
        int t = (threadIdx.x >= o) ? tsum[threadIdx.x - o] : 0;
        __syncthreads();
        tsum[threadIdx.x] += t;
        __syncthreads();
    }
    int texcl = tsum[threadIdx.x] - v;
    int boff = bsums[blockIdx.x];
#pragma unroll
    for (int j = 0; j < 16; j++) {
        int idx = base + threadIdx.x * 16 + j;
        if (idx < NN) {
            int val = boff + texcl + loc[j];
            row_ptr[idx] = val;
            if ((idx & 255) == 0) sub_cursor[idx >> 8] = val;
        }
    }
}

// ---------------- pass 2: refine coarse bucket -> 16 sub-buckets ----------------
// R15: load/atomic split (MLP) -- all 16 bed loads issue before the dependent
// LDS atomics (same pattern that fixed spmm1/fused2/p3).

__global__ __launch_bounds__(256) void p2r_k(const int* __restrict__ bkt_cursor,
                                             const int2* __restrict__ bed,
                                             int* __restrict__ sub_cursor,
                                             int2* __restrict__ mid) {
    __shared__ int lcnt[16], lbase[16], sbase[16];
    __shared__ int2 stage[4096];
    int b = blockIdx.y;
    int e1 = bkt_cursor[b];
    int base = b * BKCAP + blockIdx.x * 4096;
    if (base >= e1) return;
    if (threadIdx.x < 16) lcnt[threadIdx.x] = 0;
    __syncthreads();
    u32 pk[16]; int dv[16]; int sb[16], rk[16];
    // phase 1: issue all 16 independent loads
#pragma unroll
    for (int j = 0; j < 16; j++) {
        int e = base + j * 256 + threadIdx.x;
        sb[j] = -1;
        if (e < e1) {
            int2 d = bed[e];
            pk[j] = (u32)d.x;
            dv[j] = d.y;
            sb[j] = 0;
        }
    }
    // phase 2: LDS atomics (consume)
#pragma unroll
    for (int j = 0; j < 16; j++) {
        if (sb[j] >= 0) {
            int s = (int)((pk[j] >> 27) & 15u);   // row_local >> 8
            sb[j] = s;
            rk[j] = atomicAdd(&lcnt[s], 1);
        }
    }
    __syncthreads();
    if (threadIdx.x == 0) {
        int acc = 0;
#pragma unroll
        for (int s = 0; s < 16; s++) { sbase[s] = acc; acc += lcnt[s]; }
    }
    if (threadIdx.x < 16)
        lbase[threadIdx.x] = atomicAdd(&sub_cursor[b * 16 + threadIdx.x], lcnt[threadIdx.x]);
    __syncthreads();
#pragma unroll
    for (int j = 0; j < 16; j++)
        if (sb[j] >= 0)
            stage[sbase[sb[j]] + rk[j]] = make_int2((int)pk[j], dv[j]);
    __syncthreads();
    for (int s = 0; s < 16; s++) {
        int c = lcnt[s], gb = lbase[s], lb = sbase[s];
        for (int i = threadIdx.x; i < c; i += 256)
            mid[gb + i] = stage[lb + i];
    }
}

// ---------------- pass 3: exact row sort inside one sub-bucket (all in LDS) ----------------
// NOTE: mid aliases edge_s (in-place): all reads complete before the barrier, writes after.
// Load loop 4-batched (MLP) -- the atomic/store pairs consume after 4 loads issue.

__global__ __launch_bounds__(256) void p3_k(const int* __restrict__ row_ptr,
                                            const int2* __restrict__ mid,
                                            int2* __restrict__ edge_s) {
    __shared__ int rbase[256], rcur[256];
    __shared__ int2 stage[SUBCAP];
    int s = blockIdx.x;
    int r0 = s << 8;
    if (r0 >= NN) return;
    int r1 = min(r0 + 256, NN);
    int nr = r1 - r0;
    int ebase = row_ptr[r0];
    int eend  = row_ptr[r1];
    int cnt = eend - ebase;
    if (threadIdx.x < nr) {
        rbase[threadIdx.x] = row_ptr[r0 + threadIdx.x] - ebase;
        rcur[threadIdx.x] = 0;
    }
    __syncthreads();
    int i = threadIdx.x;
    for (; i + 768 < cnt; i += 1024) {
        int2 d0 = mid[ebase + i];
        int2 d1 = mid[ebase + i + 256];
        int2 d2 = mid[ebase + i + 512];
        int2 d3 = mid[ebase + i + 768];
        int l0 = (int)(((u32)d0.x >> 19) & 255u);
        int p0 = rbase[l0] + atomicAdd(&rcur[l0], 1);
        if (p0 < SUBCAP) stage[p0] = make_int2(d0.x & 0x7FFFF, d0.y);
        int l1 = (int)(((u32)d1.x >> 19) & 255u);
        int p1 = rbase[l1] + atomicAdd(&rcur[l1], 1);
        if (p1 < SUBCAP) stage[p1] = make_int2(d1.x & 0x7FFFF, d1.y);
        int l2 = (int)(((u32)d2.x >> 19) & 255u);
        int p2 = rbase[l2] + atomicAdd(&rcur[l2], 1);
        if (p2 < SUBCAP) stage[p2] = make_int2(d2.x & 0x7FFFF, d2.y);
        int l3 = (int)(((u32)d3.x >> 19) & 255u);
        int p3 = rbase[l3] + atomicAdd(&rcur[l3], 1);
        if (p3 < SUBCAP) stage[p3] = make_int2(d3.x & 0x7FFFF, d3.y);
    }
    for (; i < cnt; i += 256) {
        int2 d = mid[ebase + i];
        int l = (int)(((u32)d.x >> 19) & 255u);
        int pos = rbase[l] + atomicAdd(&rcur[l], 1);
        if (pos < SUBCAP) stage[pos] = make_int2(d.x & 0x7FFFF, d.y);
    }
    __syncthreads();
    for (int j = threadIdx.x; j < cnt; j += 256) edge_s[ebase + j] = stage[j];
}

// ---------------- SpMM cores: wave = 1 row, 4 subgroups x 16 lanes ----------------
// Batched-MLP: issue 8 independent edge loads, then 8 independent row gathers
// (masked slots zeroed), THEN decode. FROZEN: R3 (2-row), R5 (nt-loads), R13
// (persistent grid) all regressed >20% -- fire-and-forget small blocks keep the
// CU fed with fresh independent waves; VGPR 36 / occupancy 70% is the optimum.

struct acc8 { float a[8]; };

__device__ __forceinline__ void red8(acc8& A) {
#pragma unroll
    for (int k = 0; k < 8; k++) {
        A.a[k] += __shfl_xor(A.a[k], 16);
        A.a[k] += __shfl_xor(A.a[k], 32);
    }
}

// fp8-input core (layer 1 and layer 2): 128B = one cache line per edge gather
__device__ __forceinline__ void rg8_core(const int2* __restrict__ edge_s,
                                         const unsigned char* __restrict__ xf,
                                         int t, int g, int e0, int e1, acc8& A) {
#pragma unroll
    for (int k = 0; k < 8; k++) A.a[k] = 0.f;
    const unsigned char* xt = xf + t * 8;
    int d = e1 - e0;

    int2 ed[8];
    uint2 pv[8];
#pragma unroll
    for (int q = 0; q < 8; q++) { ed[q] = make_int2(0, 0); pv[q] = make_uint2(0u, 0u); }
#pragma unroll
    for (int q = 0; q < 8; q++) {
        int j = g + 4 * q;
        if (j < d) ed[q] = edge_s[e0 + j];
    }
#pragma unroll
    for (int q = 0; q < 8; q++) {
        int j = g + 4 * q;
        if (j < d) pv[q] = *(const uint2*)(xt + (size_t)((u32)ed[q].x * 128u));
    }
#pragma unroll
    for (int q = 0; q < 8; q++) {
        float v = __int_as_float(ed[q].y);   // 0.0f for masked slots
        float f[8];
        dec_fp8x4(pv[q].x, f);
        dec_fp8x4(pv[q].y, f + 4);
#pragma unroll
        for (int k = 0; k < 8; k++) A.a[k] += v * f[k];
    }
    // tail: edges 32..d-1 (deg ~ Poisson(21.3), rare)
    for (int e = e0 + 32 + g * 4; e < e1; e += 16) {
        int m = e1 - e;   // subgroup-uniform
#pragma unroll
        for (int k = 0; k < 4; k++) {
            if (k < m) {
                int2 dd = edge_s[e + k];
                float v = __int_as_float(dd.y);
                uint2 p = *(const uint2*)(xt + (size_t)((u32)dd.x * 128u));
                float f[8];
                dec_fp8x4(p.x, f);
                dec_fp8x4(p.y, f + 4);
#pragma unroll
                for (int q = 0; q < 8; q++) A.a[q] += v * f[q];
            }
        }
    }
    red8(A);
}

// layer 1: full graph; writes fp8 x1 mirror for ALL rows (gather source for layer 2)
// and bf16 x1 ONLY for batch rows (gadd reads just those 8192 -> 97% write cut).
// The gate lives in the epilogue (after red8): no effect on loop VGPR watermark.
__global__ __launch_bounds__(256) void spmm1_k(const int* __restrict__ row_ptr,
                                               const int2* __restrict__ edge_s,
                                               const unsigned char* __restrict__ x0f,
                                               const unsigned char* __restrict__ bmark,
                                               u16* __restrict__ y,
                                               unsigned char* __restrict__ yf) {
    int lane = threadIdx.x & 63;
    int t = lane & 15, g = lane >> 4;
    int r = blockIdx.x * 4 + (threadIdx.x >> 6);
    if (r >= NN) return;
    acc8 A;
    rg8_core(edge_s, x0f, t, g, row_ptr[r], row_ptr[r + 1], A);
    if (g == 0) {
        uint2 of;
        of.x = pack4_fp8(A.a[0], A.a[1], A.a[2], A.a[3]);
        of.y = pack4_fp8(A.a[4], A.a[5], A.a[6], A.a[7]);
        *(uint2*)(yf + (size_t)r * 128 + t * 8) = of;
        if (bmark[r]) {
            uint4 o;
            o.x = ((u32)f2bf(A.a[1]) << 16) | (u32)f2bf(A.a[0]);
            o.y = ((u32)f2bf(A.a[3]) << 16) | (u32)f2bf(A.a[2]);
            o.z = ((u32)f2bf(A.a[5]) << 16) | (u32)f2bf(A.a[4]);
            o.w = ((u32)f2bf(A.a[7]) << 16) | (u32)f2bf(A.a[6]);
            *(uint4*)(y + (size_t)r * 128 + t * 8) = o;
        }
    }
}

// bf16-input core (layer 3)
__device__ __forceinline__ void rg16_core(const int2* __restrict__ edge_s,
                                          const u16* __restrict__ x,
                                          int t, int g, int e0, int e1, acc8& A) {
#pragma unroll
    for (int k = 0; k < 8; k++) A.a[k] = 0.f;
    const u16* xt = x + t * 8;
    int d = e1 - e0;

    int2 ed[8];
    uint4 pv[8];
#pragma unroll
    for (int q = 0; q < 8; q++) { ed[q] = make_int2(0, 0); pv[q] = make_uint4(0u, 0u, 0u, 0u); }
#pragma unroll
    for (int q = 0; q < 8; q++) {
        int j = g + 4 * q;
        if (j < d) ed[q] = edge_s[e0 + j];
    }
#pragma unroll
    for (int q = 0; q < 8; q++) {
        int j = g + 4 * q;
        if (j < d) pv[q] = *(const uint4*)(xt + (size_t)(u32)ed[q].x * 128);
    }
#pragma unroll
    for (int q = 0; q < 8; q++) {
        float v = __int_as_float(ed[q].y);   // 0.0f for masked slots
        A.a[0] += v * __uint_as_float(pv[q].x << 16);
        A.a[1] += v * __uint_as_float(pv[q].x & 0xFFFF0000u);
        A.a[2] += v * __uint_as_float(pv[q].y << 16);
        A.a[3] += v * __uint_as_float(pv[q].y & 0xFFFF0000u);
        A.a[4] += v * __uint_as_float(pv[q].z << 16);
        A.a[5] += v * __uint_as_float(pv[q].z & 0xFFFF0000u);
        A.a[6] += v * __uint_as_float(pv[q].w << 16);
        A.a[7] += v * __uint_as_float(pv[q].w & 0xFFFF0000u);
    }
    // tail: edges 32..d-1
    for (int e = e0 + 32 + g * 4; e < e1; e += 16) {
        int m = e1 - e;
#pragma unroll
        for (int k = 0; k < 4; k++) {
            if (k < m) {
                int2 dd = edge_s[e + k];
                float v = __int_as_float(dd.y);
                uint4 p = *(const uint4*)(xt + (size_t)(u32)dd.x * 128);
                A.a[0] += v * __uint_as_float(p.x << 16);
                A.a[1] += v * __uint_as_float(p.x & 0xFFFF0000u);
                A.a[2] += v * __uint_as_float(p.y << 16);
                A.a[3] += v * __uint_as_float(p.y & 0xFFFF0000u);
                A.a[4] += v * __uint_as_float(p.z << 16);
                A.a[5] += v * __uint_as_float(p.z & 0xFFFF0000u);
                A.a[6] += v * __uint_as_float(p.w << 16);
                A.a[7] += v * __uint_as_float(p.w & 0xFFFF0000u);
            }
        }
    }
    red8(A);
}

// layer 2: frontier rows only; gathers fp8 x1 mirror, writes bf16 x2
__global__ __launch_bounds__(256) void spmm_list_k(const int* __restrict__ row_ptr,
                                                   const int2* __restrict__ edge_s,
                                                   const unsigned char* __restrict__ x1f,
                                                   u16* __restrict__ y,
                                                   const int* __restrict__ list2,
                                                   const int* __restrict__ nlist) {
    int lane = threadIdx.x & 63;
    int t = lane & 15, g = lane >> 4;
    int slot = blockIdx.x * 4 + (threadIdx.x >> 6);
    if (slot >= *nlist) return;
    int r = list2[slot];
    acc8 A;
    rg8_core(edge_s, x1f, t, g, row_ptr[r], row_ptr[r + 1], A);
    if (g == 0) {
        uint4 o;
        o.x = ((u32)f2bf(A.a[1]) << 16) | (u32)f2bf(A.a[0]);
        o.y = ((u32)f2bf(A.a[3]) << 16) | (u32)f2bf(A.a[2]);
        o.z = ((u32)f2bf(A.a[5]) << 16) | (u32)f2bf(A.a[4]);
        o.w = ((u32)f2bf(A.a[7]) << 16) | (u32)f2bf(A.a[6]);
        *(uint4*)(y + (size_t)r * 128 + t * 8) = o;
    }
}

// ---------------- gadd: add bf16 x1[node] into out_acc (batch rows) ----------------

__global__ void gadd_k(const int* __restrict__ user_idx, const int* __restrict__ item_idx,
                       const u16* __restrict__ x, float* __restrict__ out_acc) {
    int t = blockIdx.x * blockDim.x + threadIdx.x;   // 2B*64 threads
    int slot = t >> 6;
    int l = t & 63;
    if (slot >= 2 * BB) return;
    int node = (slot < BB) ? user_idx[slot] : U_N + item_idx[slot - BB];
    u32 p = *(const u32*)(x + (size_t)node * 128 + (l << 1));
    float fx = __uint_as_float(p << 16);
    float fy = __uint_as_float(p & 0xFFFF0000u);
    float2* q = (float2*)(out_acc + (size_t)slot * 128) + l;
    float2 cur = *q;
    cur.x += fx; cur.y += fy;
    *q = cur;
}

// ---------------- fused last layer + epilogue: x3 + (x0+x1+x2) -> preds + targets ----
// R15: spmm_last merged into pred. Wave rl computes x3 for its slot via rg16_core
// (body untouched), adds x2[r] (bf16) + out_acc[slot] (x0+x1) in registers, feeds
// uld (cols 0..63) and target stores (cols 64..127) directly -- no out_acc RMW.

__global__ __launch_bounds__(256) void last_pred_k(const int* __restrict__ row_ptr,
                                                   const int2* __restrict__ edge_s,
                                                   const u16* __restrict__ x,
                                                   const int* __restrict__ user_idx,
                                                   const int* __restrict__ item_idx,
                                                   const float* __restrict__ out_acc,
                                                   const float* __restrict__ W,
                                                   const float* __restrict__ bias,
                                                   float* __restrict__ out) {
    __shared__ float wld[64 * 65];   // W transposed, padded
    __shared__ float uld[4 * 64];
    for (int i = threadIdx.x; i < 4096; i += 256) {
        int jj = i >> 6, kk = i & 63;
        wld[kk * 65 + jj] = W[i];
    }
    int lane = threadIdx.x & 63;
    int t = lane & 15, g = lane >> 4;
    int rl = threadIdx.x >> 6;
    int slot = blockIdx.x * 4 + rl;
    int r = (slot < BB) ? user_idx[slot] : U_N + item_idx[slot - BB];
    acc8 A;
    rg16_core(edge_s, x, t, g, row_ptr[r], row_ptr[r + 1], A);
    if (g == 0) {
        // add x2[r] (bf16) + out_acc[slot] (x0+x1), scale by 1/(L+1)
        uint4 p = *(const uint4*)(x + (size_t)r * 128 + t * 8);
        A.a[0] += __uint_as_float(p.x << 16);
        A.a[1] += __uint_as_float(p.x & 0xFFFF0000u);
        A.a[2] += __uint_as_float(p.y << 16);
        A.a[3] += __uint_as_float(p.y & 0xFFFF0000u);
        A.a[4] += __uint_as_float(p.z << 16);
        A.a[5] += __uint_as_float(p.z & 0xFFFF0000u);
        A.a[6] += __uint_as_float(p.w << 16);
        A.a[7] += __uint_as_float(p.w & 0xFFFF0000u);
        const float4* p0 = (const float4*)(out_acc + (size_t)slot * 128 + t * 8);
        float4 c0 = p0[0], c1 = p0[1];
        float s0 = (c0.x + A.a[0]) * 0.25f;
        float s1 = (c0.y + A.a[1]) * 0.25f;
        float s2 = (c0.z + A.a[2]) * 0.25f;
        float s3 = (c0.w + A.a[3]) * 0.25f;
        float s4 = (c1.x + A.a[4]) * 0.25f;
        float s5 = (c1.y + A.a[5]) * 0.25f;
        float s6 = (c1.z + A.a[6]) * 0.25f;
        float s7 = (c1.w + A.a[7]) * 0.25f;
        if (t < 8) {
            // cols t*8 .. t*8+7 (< 64): pred input
            float* u = uld + rl * 64 + t * 8;
            u[0] = s0; u[1] = s1; u[2] = s2; u[3] = s3;
            u[4] = s4; u[5] = s5; u[6] = s6; u[7] = s7;
        } else {
            // cols 64..127: target output (scaled)
            int col = (t - 8) * 8;
            size_t tb = (slot < BB) ? (size_t)BB * 64 + (size_t)slot * 64
                                    : (size_t)3 * BB * 64 + (size_t)(slot - BB) * 64;
            float* o = out + tb + col;
            o[0] = s0; o[1] = s1; o[2] = s2; o[3] = s3;
            o[4] = s4; o[5] = s5; o[6] = s6; o[7] = s7;
        }
    }
    __syncthreads();
    int j = lane;
    float acc = bias[j];
#pragma unroll
    for (int k = 0; k < 64; k++) acc += uld[rl * 64 + k] * wld[k * 65 + j];
    size_t dst = (slot < BB) ? (size_t)slot * 64 + j
                             : (size_t)2 * BB * 64 + (size_t)(slot - BB) * 64 + j;
    out[dst] = acc;
}

// ---------------- launch ----------------

extern "C" void kernel_launch(void* const* d_in, const int* in_sizes, int n_in,
                              void* d_out, int out_size, void* d_ws, size_t ws_size,
                              hipStream_t stream) {
    const float* ue_on = (const float*)d_in[0];
    const float* ie_on = (const float*)d_in[1];
    const float* ue_tg = (const float*)d_in[2];
    const float* ie_tg = (const float*)d_in[3];
    const float* adj_val = (const float*)d_in[4];
    const float* pred_w = (const float*)d_in[5];
    const float* pred_b = (const float*)d_in[6];
    const int* adj_row = (const int*)d_in[7];
    const int* adj_col = (const int*)d_in[8];
    const int* user_idx = (const int*)d_in[9];
    const int* item_idx = (const int*)d_in[10];
    float* out = (float*)d_out;

    char* ws = (char*)d_ws;
    size_t off = 0;
    auto alloc = [&](size_t bytes) -> char* {
        char* p = ws + off;
        off = (off + bytes + 255) & ~(size_t)255;
        return p;
    };
    int*   cnt        = (int*)alloc((size_t)NN * 4);
    int*   row_ptr    = (int*)alloc((size_t)(NN + 1) * 4);
    int*   bsums      = (int*)alloc(256 * 4);
    int*   bkt_cursor = (int*)alloc(256 * 4);
    int*   sub_cursor = (int*)alloc((size_t)NSB * 4);
    unsigned char* mark = (unsigned char*)alloc((size_t)NN);
    unsigned char* bmark = (unsigned char*)alloc((size_t)NN);
    int*   list2      = (int*)alloc((size_t)NN * 4);
    int*   nlist      = (int*)alloc(256 * 4);
    int2*  edge_s     = (int2*)alloc((size_t)NNZ_N * 8);
    u16*   x_a        = (u16*)alloc((size_t)NN * 128 * 2);
    u16*   x_b        = (u16*)alloc((size_t)NN * 128 * 2);
    float* out_acc    = (float*)alloc((size_t)2 * BB * 128 * 4);

    // aliases (all consumed before their underlying role begins):
    //   x0f  -> x_a [0, 38.4MB)       (pack1 in fused1; dead after spmm1)
    //   x1f  -> x_a [38.4, 76.8MB)    fp8 mirror of x1 (spmm1 -> spmm_list)
    //   bed  -> x_b [0, 51.2MB)       packed (pk,val) int2 pairs (dead after p2r;
    //                                  precedes x_b's bf16 roles: x1 batch rows
    //                                  (spmm1 -> gadd), then x2 frontier rows
    //                                  (spmm_list -> last_pred))
    //   mid  -> edge_s                (in-place: p3 stages whole sub-bucket in LDS
    //                                  behind a barrier before writing back)
    unsigned char* x0f = (unsigned char*)x_a;
    unsigned char* x1f = (unsigned char*)x_a + (size_t)NN * 128;
    int2*  bed  = (int2*)x_b;
    int2*  mid  = edge_s;

    (void)n_in; (void)in_sizes; (void)out_size; (void)ws_size;

    // 1. setup + batch flags, then fused {CSR scatter + frontier mark + fp8 pack + acc init}
    setup_k<<<294, 256, 0, stream>>>(mark, bmark, nlist, bkt_cursor);
    bmark_k<<<(2 * BB) / 256, 256, 0, stream>>>(user_idx, item_idx, mark, bmark);
    fused1_k<<<P1B + PACKB + ACCB, 512, 0, stream>>>(adj_row, adj_col, adj_val,
                                                     bkt_cursor, bed, bmark, mark,
                                                     ue_on, ie_on, ue_tg, ie_tg, x0f,
                                                     user_idx, item_idx, out_acc);

    // 2. per-bucket histogram + bucket scan + frontier compact, then row scan, 2-stage sort
    fused2_k<<<NBK + 1 + CPB, 1024, 0, stream>>>(bkt_cursor, bed, cnt, bsums, row_ptr,
                                                 mark, list2, nlist);
    scan3_k<<<NB, 256, 0, stream>>>(cnt, bsums, row_ptr, sub_cursor);
    p2r_k<<<dim3(BKBLK, NBK), 256, 0, stream>>>(bkt_cursor, bed, sub_cursor, mid);
    p3_k<<<NSB, 256, 0, stream>>>(row_ptr, mid, edge_s);

    // 3. layer 1 (full, fp8 gathers, dual output), gadd x1, layer 2 (frontier, fp8),
    //    fused layer 3 + epilogue
    spmm1_k<<<NN / 4, 256, 0, stream>>>(row_ptr, edge_s, x0f, bmark, x_b, x1f);
    gadd_k<<<(2 * BB * 64) / 256, 256, 0, stream>>>(user_idx, item_idx, x_b, out_acc);
    spmm_list_k<<<LBLK, 256, 0, stream>>>(row_ptr, edge_s, x1f, x_b, list2, nlist);
    last_pred_k<<<(2 * BB) / 4, 256, 0, stream>>>(row_ptr, edge_s, x_b, user_idx, item_idx,
                                                  out_acc, pred_w, pred_b, out);
}

// Round 16
// 697.618 us; speedup vs baseline: 1.0092x; 1.0092x over previous
//
#include <hip/hip_runtime.h>
#include <hip/hip_bf16.h>
#include <stdint.h>

#define U_N   100000
#define I_N   200000
#define NN    300000
#define DD    64
#define NNZ_N 6400000
#define BB    4096
#define CHUNK 4096
#define NB    ((NN + CHUNK - 1) / CHUNK)   // 74 scan blocks
#define NBK   74                           // coarse buckets of 4096 rows
#define EPB   8192                         // edges per pass-1 block (512 thr x 16)
#define NSB   1184                         // 74*16 sub-buckets of 256 rows
#define SUBCAP 6656                        // max edges per sub-bucket (mean 5406, +17 sigma)
#define BKCAP  94208                       // fixed bucket capacity = 23*4096 (mean 87381, +23 sigma)
#define BKBLK  23                          // p2r blocks per bucket = BKCAP/4096
#define LBLK   48000                       // spmm_list grid: 192000 slots >= nlist
#define P1B   ((NNZ_N + EPB - 1) / EPB)    // 782 p1 blocks
#define PACKB ((NN * 16) / 512)            // 9375 pack blocks (512 thr)
#define ACCB  ((2 * BB * 32) / 512)        // 512 init_acc blocks (512 thr)
#define CPB   ((NN + 1023) / 1024)         // 293 compact blocks (1024 thr, in fused2)

typedef unsigned short u16;
typedef unsigned int   u32;
typedef float vf2 __attribute__((ext_vector_type(2)));

__device__ __forceinline__ u16 f2bf(float f) {
    u32 u = __float_as_uint(f);
    u32 r = (u + 0x7FFFu + ((u >> 16) & 1u)) >> 16;
    return (u16)r;
}

// ---------------- fp8 e4m3fn encode/decode (OCP; HW converts on gfx950) ----------------

#if __has_builtin(__builtin_amdgcn_cvt_pk_f32_fp8) && __has_builtin(__builtin_amdgcn_cvt_pk_fp8_f32)
#define FP8_HW 1
#else
#define FP8_HW 0
#endif

__device__ __forceinline__ u32 enc1_fp8(float f) {
    float af = fabsf(f);
    u32 s = (__float_as_uint(f) >> 31) << 7;
    if (af >= 0.015625f) {
        u32 au = __float_as_uint(af);
        u32 r = au + 0x7FFFFu + ((au >> 20) & 1u);
        u32 e = (r >> 23) - 120u;
        u32 m = (r >> 20) & 7u;
        if (e > 15u) { e = 15u; m = 6u; }
        return s | (e << 3) | m;
    } else {
        u32 q = (u32)__float2int_rn(af * 512.0f);   // RNE into subnormal grid 2^-9
        return s | q;
    }
}

__device__ __forceinline__ u32 pack4_fp8(float a, float b, float c, float d) {
#if FP8_HW
    u32 w = 0;
    w = (u32)__builtin_amdgcn_cvt_pk_fp8_f32(a, b, (int)w, false);
    w = (u32)__builtin_amdgcn_cvt_pk_fp8_f32(c, d, (int)w, true);
    return w;
#else
    return enc1_fp8(a) | (enc1_fp8(b) << 8) | (enc1_fp8(c) << 16) | (enc1_fp8(d) << 24);
#endif
}

__device__ __forceinline__ float dec1_fp8(u32 b) {
    u32 s = (b & 0x80u) << 24;
    u32 e = (b >> 3) & 15u;
    u32 m = b & 7u;
    float mag = e ? __uint_as_float(((e + 120u) << 23) | (m << 20))
                  : (float)m * 0.001953125f;   // 2^-9
    return __uint_as_float(__float_as_uint(mag) | s);
}

__device__ __forceinline__ void dec_fp8x4(u32 w, float* f) {
#if FP8_HW
    vf2 lo = __builtin_amdgcn_cvt_pk_f32_fp8((int)w, false);
    vf2 hi = __builtin_amdgcn_cvt_pk_f32_fp8((int)w, true);
    f[0] = lo[0]; f[1] = lo[1]; f[2] = hi[0]; f[3] = hi[1];
#else
    f[0] = dec1_fp8(w & 255u); f[1] = dec1_fp8((w >> 8) & 255u);
    f[2] = dec1_fp8((w >> 16) & 255u); f[3] = dec1_fp8(w >> 24);
#endif
}

// ---------------- setup: zero mark/bmark/nlist + bucket cursor init --------

__global__ void setup_k(unsigned char* __restrict__ mark, unsigned char* __restrict__ bmark,
                        int* __restrict__ nlist, int* __restrict__ bkt_cursor) {
    int tid = blockIdx.x * 256 + threadIdx.x;
    if (tid < NN / 4) { ((u32*)mark)[tid] = 0; ((u32*)bmark)[tid] = 0; }
    if (tid < NBK) bkt_cursor[tid] = tid * BKCAP;
    if (tid == NN / 4) nlist[0] = 0;
}

// bmark: batch-node flags (read by p1's frontier-marking and spmm1's bf16 gate)

__global__ void bmark_k(const int* __restrict__ user_idx, const int* __restrict__ item_idx,
                        unsigned char* __restrict__ mark, unsigned char* __restrict__ bmark) {
    int slot = blockIdx.x * 256 + threadIdx.x;
    if (slot >= 2 * BB) return;
    int r = (slot < BB) ? user_idx[slot] : U_N + item_idx[slot - BB];
    bmark[r] = 1;
    mark[r] = 1;
}

// ---------------- fused1: p1 bucket scatter + frontier mark + pack1 fp8 + init_acc ----
// 512-thread blocks: p1's per-bucket scatter chunk ~880B contiguous (R8/R10
// mechanism). Per-thread depth stays 16 (R3/R5: deeper starves VGPRs).
// payload: bed[p] = { pk = (row&4095)<<19 | col, val } -- ONE 8B store per edge.

__global__ __launch_bounds__(512) void fused1_k(const int* __restrict__ adj_row,
                                                const int* __restrict__ adj_col,
                                                const float* __restrict__ adj_val,
                                                int* __restrict__ bkt_cursor,
                                                int2* __restrict__ bed,
                                                const unsigned char* __restrict__ bmark,
                                                unsigned char* __restrict__ mark,
                                                const float* __restrict__ ue_on,
                                                const float* __restrict__ ie_on,
                                                const float* __restrict__ ue_tg,
                                                const float* __restrict__ ie_tg,
                                                unsigned char* __restrict__ x0f,
                                                const int* __restrict__ user_idx,
                                                const int* __restrict__ item_idx,
                                                float* __restrict__ out_acc) {
    __shared__ int lcnt[NBK];
    __shared__ int lbase[NBK];
    int bid = blockIdx.x;
    if (bid < P1B) {
        // ---- p1 body (512 threads x 16 edges) ----
        int base = bid * EPB;
        for (int i = threadIdx.x; i < NBK; i += 512) lcnt[i] = 0;
        __syncthreads();
        u32 pk[16]; float vv[16]; int bb[16]; int rk[16];
#pragma unroll
        for (int j = 0; j < 16; j++) {
            int e = base + j * 512 + threadIdx.x;
            bb[j] = -1;
            if (e < NNZ_N) {
                int r = adj_row[e];
                int c = adj_col[e];
                vv[j] = adj_val[e];
                int b = r >> 12;
                pk[j] = ((u32)(r & 4095) << 19) | (u32)c;
                bb[j] = b;
                rk[j] = atomicAdd(&lcnt[b], 1);
                if (bmark[r]) mark[c] = 1;   // fused frontier mark
            }
        }
        __syncthreads();
        for (int i = threadIdx.x; i < NBK; i += 512)
            lbase[i] = atomicAdd(&bkt_cursor[i], lcnt[i]);
        __syncthreads();
#pragma unroll
        for (int j = 0; j < 16; j++) {
            if (bb[j] >= 0) {
                int p = lbase[bb[j]] + rk[j];
                bed[p] = make_int2((int)pk[j], __float_as_int(vv[j]));
            }
        }
        return;
    }
    bid -= P1B;
    if (bid < PACKB) {
        // ---- pack1 body: x0 as fp8 e4m3fn [N,128] ----
        int tid = bid * 512 + threadIdx.x;   // NN*16 threads
        int n = tid >> 4;
        int t = tid & 15;
        if (n >= NN) return;
        const float* src;
        int soff;
        if (t < 8) {
            soff = t * 8;
            src = (n < U_N) ? ue_on + (size_t)n * 64 : ie_on + (size_t)(n - U_N) * 64;
        } else {
            soff = (t - 8) * 8;
            src = (n < U_N) ? ue_tg + (size_t)n * 64 : ie_tg + (size_t)(n - U_N) * 64;
        }
        float4 f0 = *(const float4*)(src + soff);
        float4 f1 = *(const float4*)(src + soff + 4);
        uint2 o;
        o.x = pack4_fp8(f0.x, f0.y, f0.z, f0.w);
        o.y = pack4_fp8(f1.x, f1.y, f1.z, f1.w);
        *(uint2*)(x0f + (size_t)n * 128 + t * 8) = o;
        return;
    }
    bid -= PACKB;
    {
        // ---- init_acc body ----
        int t = bid * 512 + threadIdx.x;   // 2B*32 threads
        int slot = t >> 5;
        int j = t & 31;
        if (slot >= 2 * BB) return;
        int node = (slot < BB) ? user_idx[slot] : U_N + item_idx[slot - BB];
        const float* src;
        int soff, doff;
        if (j < 16) {
            soff = j * 4; doff = j * 4;
            src = (node < U_N) ? ue_on + (size_t)node * 64 : ie_on + (size_t)(node - U_N) * 64;
        } else {
            soff = (j - 16) * 4; doff = 64 + (j - 16) * 4;
            src = (node < U_N) ? ue_tg + (size_t)node * 64 : ie_tg + (size_t)(node - U_N) * 64;
        }
        float4 f = *(const float4*)(src + soff);
        *(float4*)(out_acc + (size_t)slot * 128 + doff) = f;
    }
}

// ---------------- fused2: per-bucket LDS histogram + bucket scan + frontier compact ----
// blocks [0,NBK): histogram (int4 pair-loads x4 unroll, 8 edges in flight/thread);
// block NBK: bucket-total exclusive scan; blocks NBK+1..NBK+CPB: compact (1024-thr).

__global__ __launch_bounds__(1024) void fused2_k(const int* __restrict__ bkt_cursor,
                                                 const int2* __restrict__ bed,
                                                 int* __restrict__ cnt,
                                                 int* __restrict__ bsums,
                                                 int* __restrict__ row_ptr,
                                                 const unsigned char* __restrict__ mark,
                                                 int* __restrict__ list2,
                                                 int* __restrict__ nlist) {
    if (blockIdx.x < NBK) {
        __shared__ int h[4096];
        int b = blockIdx.x;
        int base = b * BKCAP;
        int e1 = bkt_cursor[b];            // base + cnt_b after p1
        int len = e1 - base;
        for (int j = threadIdx.x; j < 4096; j += 1024) h[j] = 0;
        __syncthreads();
        const int4* bed4 = (const int4*)(bed + base);   // edge pairs (BKCAP even -> aligned)
        int np = len >> 1;
        int t = threadIdx.x;
        int i = t;
        for (; i + 3072 < np; i += 4096) {
            int4 a  = bed4[i];
            int4 b2 = bed4[i + 1024];
            int4 c2 = bed4[i + 2048];
            int4 d2 = bed4[i + 3072];
            atomicAdd(&h[(u32)a.x  >> 19], 1); atomicAdd(&h[(u32)a.z  >> 19], 1);
            atomicAdd(&h[(u32)b2.x >> 19], 1); atomicAdd(&h[(u32)b2.z >> 19], 1);
            atomicAdd(&h[(u32)c2.x >> 19], 1); atomicAdd(&h[(u32)c2.z >> 19], 1);
            atomicAdd(&h[(u32)d2.x >> 19], 1); atomicAdd(&h[(u32)d2.z >> 19], 1);
        }
        for (; i < np; i += 1024) {
            int4 a = bed4[i];
            atomicAdd(&h[(u32)a.x >> 19], 1); atomicAdd(&h[(u32)a.z >> 19], 1);
        }
        if (t == 0 && (len & 1)) atomicAdd(&h[(u32)bed[e1 - 1].x >> 19], 1);
        __syncthreads();
        int rb = b << 12;
        for (int j = threadIdx.x; j < 4096; j += 1024) {
            int idx = rb + j;
            if (idx < NN) cnt[idx] = h[j];
        }
    } else if (blockIdx.x == NBK) {
        __shared__ int sh[128];
        int t = threadIdx.x;
        int v = 0;
        if (t < 128) {
            v = (t < NB) ? bkt_cursor[t] - t * BKCAP : 0;
            sh[t] = v;
        }
        __syncthreads();
        for (int o = 1; o < 128; o <<= 1) {
            int tmp = 0;
            if (t < 128 && t >= o) tmp = sh[t - o];
            __syncthreads();
            if (t < 128) sh[t] += tmp;
            __syncthreads();
        }
        if (t < NB) bsums[t] = sh[t] - v;   // exclusive
        if (t == 127) row_ptr[NN] = sh[127]; // total = NNZ
    } else {
        // ---- compact body (frontier list from mark) ----
        int i = (blockIdx.x - NBK - 1) * 1024 + threadIdx.x;
        int lane = threadIdx.x & 63;
        int m = (i < NN) ? (int)mark[i] : 0;
        unsigned long long b = __ballot(m != 0);
        int pre = __popcll(b & ((1ull << lane) - 1ull));
        int tot = __popcll(b);
        int base = 0;
        if (lane == 0 && tot) base = atomicAdd(nlist, tot);
        base = __shfl(base, 0);
        if (m) list2[base + pre] = i;
    }
}

// scan3 also seeds sub_cursor (fused former subinit_k).
__global__ void scan3_k(const int* __restrict__ cnt, const int* __restrict__ bsums,
                        int* __restrict__ row_ptr, int* __restrict__ sub_cursor) {
    __shared__ int tsum[256];
    int base = blockIdx.x * CHUNK;
    int loc[16];
    int s = 0;
#pragma unroll
    for (int j = 0; j < 16; j++) {
        int idx = base + threadIdx.x * 16 + j;
        int c = (idx < NN) ? cnt[idx] : 0;
        loc[j] = s;
        s += c;
    }
    tsum[threadIdx.x] = s;
    __syncthreads();
    int v = s;
    for (int o = 1; o < 256; o <<= 1) {
        int t = (threadIdx.x >= o) ? tsum[threadIdx.x - o] : 0;
        __syncthreads();
        tsum[threadIdx.x] += t;
        __syncthreads();
    }
    int texcl = tsum[threadIdx.x] - v;
    int boff = bsums[blockIdx.x];
#pragma unroll
    for (int j = 0; j < 16; j++) {
        int idx = base + threadIdx.x * 16 + j;
        if (idx < NN) {
            int val = boff + texcl + loc[j];
            row_ptr[idx] = val;
            if ((idx & 255) == 0) sub_cursor[idx >> 8] = val;
        }
    }
}

// ---------------- pass 2: refine coarse bucket -> 16 sub-buckets ----------------

__global__ __launch_bounds__(256) void p2r_k(const int* __restrict__ bkt_cursor,
                                             const int2* __restrict__ bed,
                                             int* __restrict__ sub_cursor,
                                             int2* __restrict__ mid) {
    __shared__ int lcnt[16], lbase[16], sbase[16];
    __shared__ int2 stage[4096];
    int b = blockIdx.y;
    int e1 = bkt_cursor[b];
    int base = b * BKCAP + blockIdx.x * 4096;
    if (base >= e1) return;
    if (threadIdx.x < 16) lcnt[threadIdx.x] = 0;
    __syncthreads();
    u32 pk[16]; int dv[16]; int sb[16], rk[16];
#pragma unroll
    for (int j = 0; j < 16; j++) {
        int e = base + j * 256 + threadIdx.x;
        sb[j] = -1;
        if (e < e1) {
            int2 d = bed[e];
            pk[j] = (u32)d.x;
            dv[j] = d.y;
            int s = (int)((pk[j] >> 27) & 15u);   // row_local >> 8
            sb[j] = s;
            rk[j] = atomicAdd(&lcnt[s], 1);
        }
    }
    __syncthreads();
    if (threadIdx.x == 0) {
        int acc = 0;
#pragma unroll
        for (int s = 0; s < 16; s++) { sbase[s] = acc; acc += lcnt[s]; }
    }
    if (threadIdx.x < 16)
        lbase[threadIdx.x] = atomicAdd(&sub_cursor[b * 16 + threadIdx.x], lcnt[threadIdx.x]);
    __syncthreads();
#pragma unroll
    for (int j = 0; j < 16; j++)
        if (sb[j] >= 0)
            stage[sbase[sb[j]] + rk[j]] = make_int2((int)pk[j], dv[j]);
    __syncthreads();
    for (int s = 0; s < 16; s++) {
        int c = lcnt[s], gb = lbase[s], lb = sbase[s];
        for (int i = threadIdx.x; i < c; i += 256)
            mid[gb + i] = stage[lb + i];
    }
}

// ---------------- pass 3: exact row sort inside one sub-bucket (all in LDS) ----------------
// NOTE: mid aliases edge_s (in-place): all reads complete before the barrier, writes after.
// Load loop 4-batched (MLP) -- the atomic/store pairs consume after 4 loads issue.

__global__ __launch_bounds__(256) void p3_k(const int* __restrict__ row_ptr,
                                            const int2* __restrict__ mid,
                                            int2* __restrict__ edge_s) {
    __shared__ int rbase[256], rcur[256];
    __shared__ int2 stage[SUBCAP];
    int s = blockIdx.x;
    int r0 = s << 8;
    if (r0 >= NN) return;
    int r1 = min(r0 + 256, NN);
    int nr = r1 - r0;
    int ebase = row_ptr[r0];
    int eend  = row_ptr[r1];
    int cnt = eend - ebase;
    if (threadIdx.x < nr) {
        rbase[threadIdx.x] = row_ptr[r0 + threadIdx.x] - ebase;
        rcur[threadIdx.x] = 0;
    }
    __syncthreads();
    int i = threadIdx.x;
    for (; i + 768 < cnt; i += 1024) {
        int2 d0 = mid[ebase + i];
        int2 d1 = mid[ebase + i + 256];
        int2 d2 = mid[ebase + i + 512];
        int2 d3 = mid[ebase + i + 768];
        int l0 = (int)(((u32)d0.x >> 19) & 255u);
        int p0 = rbase[l0] + atomicAdd(&rcur[l0], 1);
        if (p0 < SUBCAP) stage[p0] = make_int2(d0.x & 0x7FFFF, d0.y);
        int l1 = (int)(((u32)d1.x >> 19) & 255u);
        int p1 = rbase[l1] + atomicAdd(&rcur[l1], 1);
        if (p1 < SUBCAP) stage[p1] = make_int2(d1.x & 0x7FFFF, d1.y);
        int l2 = (int)(((u32)d2.x >> 19) & 255u);
        int p2 = rbase[l2] + atomicAdd(&rcur[l2], 1);
        if (p2 < SUBCAP) stage[p2] = make_int2(d2.x & 0x7FFFF, d2.y);
        int l3 = (int)(((u32)d3.x >> 19) & 255u);
        int p3 = rbase[l3] + atomicAdd(&rcur[l3], 1);
        if (p3 < SUBCAP) stage[p3] = make_int2(d3.x & 0x7FFFF, d3.y);
    }
    for (; i < cnt; i += 256) {
        int2 d = mid[ebase + i];
        int l = (int)(((u32)d.x >> 19) & 255u);
        int pos = rbase[l] + atomicAdd(&rcur[l], 1);
        if (pos < SUBCAP) stage[pos] = make_int2(d.x & 0x7FFFF, d.y);
    }
    __syncthreads();
    for (int j = threadIdx.x; j < cnt; j += 256) edge_s[ebase + j] = stage[j];
}

// ---------------- SpMM cores: wave = 1 row, 4 subgroups x 16 lanes ----------------
// Batched-MLP: issue 8 independent edge loads, then 8 independent row gathers
// (masked slots zeroed), THEN decode. FROZEN: R3 (2-row), R5 (nt-loads), R13
// (persistent grid) all regressed >20% -- fire-and-forget small blocks keep the
// CU fed with fresh independent waves; VGPR 36 / occupancy 70% is the optimum.

struct acc8 { float a[8]; };

__device__ __forceinline__ void red8(acc8& A) {
#pragma unroll
    for (int k = 0; k < 8; k++) {
        A.a[k] += __shfl_xor(A.a[k], 16);
        A.a[k] += __shfl_xor(A.a[k], 32);
    }
}

// fp8-input core (layer 1 and layer 2): 128B = one cache line per edge gather
__device__ __forceinline__ void rg8_core(const int2* __restrict__ edge_s,
                                         const unsigned char* __restrict__ xf,
                                         int t, int g, int e0, int e1, acc8& A) {
#pragma unroll
    for (int k = 0; k < 8; k++) A.a[k] = 0.f;
    const unsigned char* xt = xf + t * 8;
    int d = e1 - e0;

    int2 ed[8];
    uint2 pv[8];
#pragma unroll
    for (int q = 0; q < 8; q++) { ed[q] = make_int2(0, 0); pv[q] = make_uint2(0u, 0u); }
#pragma unroll
    for (int q = 0; q < 8; q++) {
        int j = g + 4 * q;
        if (j < d) ed[q] = edge_s[e0 + j];
    }
#pragma unroll
    for (int q = 0; q < 8; q++) {
        int j = g + 4 * q;
        if (j < d) pv[q] = *(const uint2*)(xt + (size_t)((u32)ed[q].x * 128u));
    }
#pragma unroll
    for (int q = 0; q < 8; q++) {
        float v = __int_as_float(ed[q].y);   // 0.0f for masked slots
        float f[8];
        dec_fp8x4(pv[q].x, f);
        dec_fp8x4(pv[q].y, f + 4);
#pragma unroll
        for (int k = 0; k < 8; k++) A.a[k] += v * f[k];
    }
    // tail: edges 32..d-1 (deg ~ Poisson(21.3), rare)
    for (int e = e0 + 32 + g * 4; e < e1; e += 16) {
        int m = e1 - e;   // subgroup-uniform
#pragma unroll
        for (int k = 0; k < 4; k++) {
            if (k < m) {
                int2 dd = edge_s[e + k];
                float v = __int_as_float(dd.y);
                uint2 p = *(const uint2*)(xt + (size_t)((u32)dd.x * 128u));
                float f[8];
                dec_fp8x4(p.x, f);
                dec_fp8x4(p.y, f + 4);
#pragma unroll
                for (int q = 0; q < 8; q++) A.a[q] += v * f[q];
            }
        }
    }
    red8(A);
}

// layer 1: full graph; writes fp8 x1 mirror for ALL rows (gather source for layer 2)
// and bf16 x1 ONLY for batch rows (gadd reads just those 8192 -> 97% write cut).
// The gate lives in the epilogue (after red8): no effect on loop VGPR watermark.
__global__ __launch_bounds__(256) void spmm1_k(const int* __restrict__ row_ptr,
                                               const int2* __restrict__ edge_s,
                                               const unsigned char* __restrict__ x0f,
                                               const unsigned char* __restrict__ bmark,
                                               u16* __restrict__ y,
                                               unsigned char* __restrict__ yf) {
    int lane = threadIdx.x & 63;
    int t = lane & 15, g = lane >> 4;
    int r = blockIdx.x * 4 + (threadIdx.x >> 6);
    if (r >= NN) return;
    acc8 A;
    rg8_core(edge_s, x0f, t, g, row_ptr[r], row_ptr[r + 1], A);
    if (g == 0) {
        uint2 of;
        of.x = pack4_fp8(A.a[0], A.a[1], A.a[2], A.a[3]);
        of.y = pack4_fp8(A.a[4], A.a[5], A.a[6], A.a[7]);
        *(uint2*)(yf + (size_t)r * 128 + t * 8) = of;
        if (bmark[r]) {
            uint4 o;
            o.x = ((u32)f2bf(A.a[1]) << 16) | (u32)f2bf(A.a[0]);
            o.y = ((u32)f2bf(A.a[3]) << 16) | (u32)f2bf(A.a[2]);
            o.z = ((u32)f2bf(A.a[5]) << 16) | (u32)f2bf(A.a[4]);
            o.w = ((u32)f2bf(A.a[7]) << 16) | (u32)f2bf(A.a[6]);
            *(uint4*)(y + (size_t)r * 128 + t * 8) = o;
        }
    }
}

// bf16-input core (layer 3)
__device__ __forceinline__ void rg16_core(const int2* __restrict__ edge_s,
                                          const u16* __restrict__ x,
                                          int t, int g, int e0, int e1, acc8& A) {
#pragma unroll
    for (int k = 0; k < 8; k++) A.a[k] = 0.f;
    const u16* xt = x + t * 8;
    int d = e1 - e0;

    int2 ed[8];
    uint4 pv[8];
#pragma unroll
    for (int q = 0; q < 8; q++) { ed[q] = make_int2(0, 0); pv[q] = make_uint4(0u, 0u, 0u, 0u); }
#pragma unroll
    for (int q = 0; q < 8; q++) {
        int j = g + 4 * q;
        if (j < d) ed[q] = edge_s[e0 + j];
    }
#pragma unroll
    for (int q = 0; q < 8; q++) {
        int j = g + 4 * q;
        if (j < d) pv[q] = *(const uint4*)(xt + (size_t)(u32)ed[q].x * 128);
    }
#pragma unroll
    for (int q = 0; q < 8; q++) {
        float v = __int_as_float(ed[q].y);   // 0.0f for masked slots
        A.a[0] += v * __uint_as_float(pv[q].x << 16);
        A.a[1] += v * __uint_as_float(pv[q].x & 0xFFFF0000u);
        A.a[2] += v * __uint_as_float(pv[q].y << 16);
        A.a[3] += v * __uint_as_float(pv[q].y & 0xFFFF0000u);
        A.a[4] += v * __uint_as_float(pv[q].z << 16);
        A.a[5] += v * __uint_as_float(pv[q].z & 0xFFFF0000u);
        A.a[6] += v * __uint_as_float(pv[q].w << 16);
        A.a[7] += v * __uint_as_float(pv[q].w & 0xFFFF0000u);
    }
    // tail: edges 32..d-1
    for (int e = e0 + 32 + g * 4; e < e1; e += 16) {
        int m = e1 - e;
#pragma unroll
        for (int k = 0; k < 4; k++) {
            if (k < m) {
                int2 dd = edge_s[e + k];
                float v = __int_as_float(dd.y);
                uint4 p = *(const uint4*)(xt + (size_t)(u32)dd.x * 128);
                A.a[0] += v * __uint_as_float(p.x << 16);
                A.a[1] += v * __uint_as_float(p.x & 0xFFFF0000u);
                A.a[2] += v * __uint_as_float(p.y << 16);
                A.a[3] += v * __uint_as_float(p.y & 0xFFFF0000u);
                A.a[4] += v * __uint_as_float(p.z << 16);
                A.a[5] += v * __uint_as_float(p.z & 0xFFFF0000u);
                A.a[6] += v * __uint_as_float(p.w << 16);
                A.a[7] += v * __uint_as_float(p.w & 0xFFFF0000u);
            }
        }
    }
    red8(A);
}

// layer 2: frontier rows only; gathers fp8 x1 mirror, writes bf16 x2
__global__ __launch_bounds__(256) void spmm_list_k(const int* __restrict__ row_ptr,
                                                   const int2* __restrict__ edge_s,
                                                   const unsigned char* __restrict__ x1f,
                                                   u16* __restrict__ y,
                                                   const int* __restrict__ list2,
                                                   const int* __restrict__ nlist) {
    int lane = threadIdx.x & 63;
    int t = lane & 15, g = lane >> 4;
    int slot = blockIdx.x * 4 + (threadIdx.x >> 6);
    if (slot >= *nlist) return;
    int r = list2[slot];
    acc8 A;
    rg8_core(edge_s, x1f, t, g, row_ptr[r], row_ptr[r + 1], A);
    if (g == 0) {
        uint4 o;
        o.x = ((u32)f2bf(A.a[1]) << 16) | (u32)f2bf(A.a[0]);
        o.y = ((u32)f2bf(A.a[3]) << 16) | (u32)f2bf(A.a[2]);
        o.z = ((u32)f2bf(A.a[5]) << 16) | (u32)f2bf(A.a[4]);
        o.w = ((u32)f2bf(A.a[7]) << 16) | (u32)f2bf(A.a[6]);
        *(uint4*)(y + (size_t)r * 128 + t * 8) = o;
    }
}

// last layer: only the 8192 batch rows, fp32 accumulate into out_acc.
// gadd for x2 fused into the epilogue (adds bf16 x2[node] before the RMW).
__global__ __launch_bounds__(256) void spmm_last_k(const int* __restrict__ row_ptr,
                                                   const int2* __restrict__ edge_s,
                                                   const u16* __restrict__ x,
                                                   const int* __restrict__ user_idx,
                                                   const int* __restrict__ item_idx,
                                                   float* __restrict__ out_acc) {
    int lane = threadIdx.x & 63;
    int t = lane & 15, g = lane >> 4;
    int slot = blockIdx.x * 4 + (threadIdx.x >> 6);
    if (slot >= 2 * BB) return;
    int r = (slot < BB) ? user_idx[slot] : U_N + item_idx[slot - BB];
    acc8 A;
    rg16_core(edge_s, x, t, g, row_ptr[r], row_ptr[r + 1], A);
    if (g == 0) {
        // fused gadd: add x2[r] (bf16) into the layer-3 sums
        uint4 p = *(const uint4*)(x + (size_t)r * 128 + t * 8);
        A.a[0] += __uint_as_float(p.x << 16);
        A.a[1] += __uint_as_float(p.x & 0xFFFF0000u);
        A.a[2] += __uint_as_float(p.y << 16);
        A.a[3] += __uint_as_float(p.y & 0xFFFF0000u);
        A.a[4] += __uint_as_float(p.z << 16);
        A.a[5] += __uint_as_float(p.z & 0xFFFF0000u);
        A.a[6] += __uint_as_float(p.w << 16);
        A.a[7] += __uint_as_float(p.w & 0xFFFF0000u);
        float4* p0 = (float4*)(out_acc + (size_t)slot * 128 + t * 8);
        float4 c0 = p0[0], c1 = p0[1];
        c0.x += A.a[0]; c0.y += A.a[1]; c0.z += A.a[2]; c0.w += A.a[3];
        c1.x += A.a[4]; c1.y += A.a[5]; c1.z += A.a[6]; c1.w += A.a[7];
        p0[0] = c0; p0[1] = c1;
    }
}

// ---------------- gadd: add bf16 x1[node] into out_acc (batch rows) ----------------

__global__ void gadd_k(const int* __restrict__ user_idx, const int* __restrict__ item_idx,
                       const u16* __restrict__ x, float* __restrict__ out_acc) {
    int t = blockIdx.x * blockDim.x + threadIdx.x;   // 2B*64 threads
    int slot = t >> 6;
    int l = t & 63;
    if (slot >= 2 * BB) return;
    int node = (slot < BB) ? user_idx[slot] : U_N + item_idx[slot - BB];
    u32 p = *(const u32*)(x + (size_t)node * 128 + (l << 1));
    float fx = __uint_as_float(p << 16);
    float fy = __uint_as_float(p & 0xFFFF0000u);
    float2* q = (float2*)(out_acc + (size_t)slot * 128) + l;
    float2 cur = *q;
    cur.x += fx; cur.y += fy;
    *q = cur;
}

// ---------------- epilogue: preds (GEMM) + targets fused ----------------

__global__ __launch_bounds__(256) void pred_k(const float* __restrict__ out_acc,
                                              const float* __restrict__ W,
                                              const float* __restrict__ bias,
                                              float* __restrict__ out) {
    __shared__ float wld[64 * 65];   // W transposed, padded
    __shared__ float uld[4 * 64];
    int j = threadIdx.x & 63;
    int rl = threadIdx.x >> 6;
    for (int i = threadIdx.x; i < 4096; i += 256) {
        int jj = i >> 6, kk = i & 63;
        wld[kk * 65 + jj] = W[i];
    }
    int slot = blockIdx.x * 4 + rl;
    uld[rl * 64 + j] = out_acc[(size_t)slot * 128 + j] * 0.25f;
    // target: cols 64..127, scaled
    float tv = out_acc[(size_t)slot * 128 + 64 + j] * 0.25f;
    size_t tdst = (slot < BB) ? (size_t)BB * 64 + (size_t)slot * 64 + j
                              : (size_t)3 * BB * 64 + (size_t)(slot - BB) * 64 + j;
    out[tdst] = tv;
    __syncthreads();
    float acc = bias[j];
#pragma unroll
    for (int k = 0; k < 64; k++) acc += uld[rl * 64 + k] * wld[k * 65 + j];
    size_t dst = (slot < BB) ? (size_t)slot * 64 + j
                             : (size_t)2 * BB * 64 + (size_t)(slot - BB) * 64 + j;
    out[dst] = acc;
}

// ---------------- launch ----------------

extern "C" void kernel_launch(void* const* d_in, const int* in_sizes, int n_in,
                              void* d_out, int out_size, void* d_ws, size_t ws_size,
                              hipStream_t stream) {
    const float* ue_on = (const float*)d_in[0];
    const float* ie_on = (const float*)d_in[1];
    const float* ue_tg = (const float*)d_in[2];
    const float* ie_tg = (const float*)d_in[3];
    const float* adj_val = (const float*)d_in[4];
    const float* pred_w = (const float*)d_in[5];
    const float* pred_b = (const float*)d_in[6];
    const int* adj_row = (const int*)d_in[7];
    const int* adj_col = (const int*)d_in[8];
    const int* user_idx = (const int*)d_in[9];
    const int* item_idx = (const int*)d_in[10];
    float* out = (float*)d_out;

    char* ws = (char*)d_ws;
    size_t off = 0;
    auto alloc = [&](size_t bytes) -> char* {
        char* p = ws + off;
        off = (off + bytes + 255) & ~(size_t)255;
        return p;
    };
    int*   cnt        = (int*)alloc((size_t)NN * 4);
    int*   row_ptr    = (int*)alloc((size_t)(NN + 1) * 4);
    int*   bsums      = (int*)alloc(256 * 4);
    int*   bkt_cursor = (int*)alloc(256 * 4);
    int*   sub_cursor = (int*)alloc((size_t)NSB * 4);
    unsigned char* mark = (unsigned char*)alloc((size_t)NN);
    unsigned char* bmark = (unsigned char*)alloc((size_t)NN);
    int*   list2      = (int*)alloc((size_t)NN * 4);
    int*   nlist      = (int*)alloc(256 * 4);
    int2*  edge_s     = (int2*)alloc((size_t)NNZ_N * 8);
    u16*   x_a        = (u16*)alloc((size_t)NN * 128 * 2);
    u16*   x_b        = (u16*)alloc((size_t)NN * 128 * 2);
    float* out_acc    = (float*)alloc((size_t)2 * BB * 128 * 4);

    // aliases (all consumed before their underlying role begins):
    //   x0f  -> x_a [0, 38.4MB)       (pack1 in fused1; dead after spmm1)
    //   x1f  -> x_a [38.4, 76.8MB)    fp8 mirror of x1 (spmm1 -> spmm_list)
    //   bed  -> x_b [0, 51.2MB)       packed (pk,val) int2 pairs (dead after p2r;
    //                                  precedes x_b's bf16 roles: x1 batch rows
    //                                  (spmm1 -> gadd), then x2 frontier rows
    //                                  (spmm_list -> spmm_last))
    //   mid  -> edge_s                (in-place: p3 stages whole sub-bucket in LDS
    //                                  behind a barrier before writing back)
    unsigned char* x0f = (unsigned char*)x_a;
    unsigned char* x1f = (unsigned char*)x_a + (size_t)NN * 128;
    int2*  bed  = (int2*)x_b;
    int2*  mid  = edge_s;

    (void)n_in; (void)in_sizes; (void)out_size; (void)ws_size;

    // 1. setup + batch flags, then fused {CSR scatter + frontier mark + fp8 pack + acc init}
    setup_k<<<294, 256, 0, stream>>>(mark, bmark, nlist, bkt_cursor);
    bmark_k<<<(2 * BB) / 256, 256, 0, stream>>>(user_idx, item_idx, mark, bmark);
    fused1_k<<<P1B + PACKB + ACCB, 512, 0, stream>>>(adj_row, adj_col, adj_val,
                                                     bkt_cursor, bed, bmark, mark,
                                                     ue_on, ie_on, ue_tg, ie_tg, x0f,
                                                     user_idx, item_idx, out_acc);

    // 2. per-bucket histogram + bucket scan + frontier compact, then row scan, 2-stage sort
    fused2_k<<<NBK + 1 + CPB, 1024, 0, stream>>>(bkt_cursor, bed, cnt, bsums, row_ptr,
                                                 mark, list2, nlist);
    scan3_k<<<NB, 256, 0, stream>>>(cnt, bsums, row_ptr, sub_cursor);
    p2r_k<<<dim3(BKBLK, NBK), 256, 0, stream>>>(bkt_cursor, bed, sub_cursor, mid);
    p3_k<<<NSB, 256, 0, stream>>>(row_ptr, mid, edge_s);

    // 3. layer 1 (full, fp8 gathers, dual output), gadd x1, layer 2 (frontier, fp8),
    //    layer 3 (batch rows + fused gadd x2)
    spmm1_k<<<NN / 4, 256, 0, stream>>>(row_ptr, edge_s, x0f, bmark, x_b, x1f);
    gadd_k<<<(2 * BB * 64) / 256, 256, 0, stream>>>(user_idx, item_idx, x_b, out_acc);
    spmm_list_k<<<LBLK, 256, 0, stream>>>(row_ptr, edge_s, x1f, x_b, list2, nlist);
    spmm_last_k<<<(2 * BB) / 4, 256, 0, stream>>>(row_ptr, edge_s, x_b, user_idx, item_idx, out_acc);

    // 4. epilogue (preds + targets fused)
    pred_k<<<(2 * BB) / 4, 256, 0, stream>>>(out_acc, pred_w, pred_b, out);
}